// Round 11
// baseline (113.157 us; speedup 1.0000x reference)
//
#include <hip/hip_runtime.h>
#include <hip/hip_bf16.h>

// C[1024,16384] = l2norm_rows(inputs[1024,2048]) @ features[16384,2048]^T / 0.05
// Round 11: 32x32x16 MFMA (2382 vs 2075 TF ubench, half the issue slots) +
// 2-phase/tile schedule (4 barriers/tile, was 8) on the R5/R8-verified
// stage/vmcnt ledger. Prep pass unchanged.

typedef short  bf16x8 __attribute__((ext_vector_type(8)));
typedef float  f32x4  __attribute__((ext_vector_type(4)));
typedef float  f32x16 __attribute__((ext_vector_type(16)));

#define D_K   2048
#define N_N   16384
#define M_M   1024
#define TEMP_INV 20.0f

__device__ __forceinline__ unsigned short f2bf(float f) {
    unsigned u = __builtin_bit_cast(unsigned, f);
    u += 0x7FFFu + ((u >> 16) & 1u);   // round-to-nearest-even (finite data)
    return (unsigned short)(u >> 16);
}

#define GLOAD16(g, l) __builtin_amdgcn_global_load_lds(                        \
    (const __attribute__((address_space(1))) unsigned int*)(g),                \
    (__attribute__((address_space(3))) unsigned int*)(l), 16, 0, 0)

// ---------------- pass 1: prep = anorm (blocks 0..1023) + bconv (rest) ----
__global__ __launch_bounds__(256) void prep_kernel(const float* __restrict__ x,
                                                   const float* __restrict__ B,
                                                   unsigned short* __restrict__ abf,
                                                   unsigned short* __restrict__ bbf) {
    int t = threadIdx.x;
    if (blockIdx.x < M_M) {
        int row = blockIdx.x;
        const float4* xr = reinterpret_cast<const float4*>(x + (size_t)row * D_K);
        float4 a = xr[t * 2];
        float4 b = xr[t * 2 + 1];
        float s = a.x*a.x + a.y*a.y + a.z*a.z + a.w*a.w
                + b.x*b.x + b.y*b.y + b.z*b.z + b.w*b.w;
        #pragma unroll
        for (int off = 32; off > 0; off >>= 1) s += __shfl_down(s, off);
        __shared__ float ps[4];
        __shared__ float sbc;
        if ((t & 63) == 0) ps[t >> 6] = s;
        __syncthreads();
        if (t == 0) {
            float tot = ps[0] + ps[1] + ps[2] + ps[3];
            sbc = 1.0f / fmaxf(sqrtf(tot), 1e-12f);
        }
        __syncthreads();
        float rs = sbc;
        bf16x8 v;
        v[0] = (short)f2bf(a.x * rs); v[1] = (short)f2bf(a.y * rs);
        v[2] = (short)f2bf(a.z * rs); v[3] = (short)f2bf(a.w * rs);
        v[4] = (short)f2bf(b.x * rs); v[5] = (short)f2bf(b.y * rs);
        v[6] = (short)f2bf(b.z * rs); v[7] = (short)f2bf(b.w * rs);
        *reinterpret_cast<bf16x8*>(abf + (size_t)row * D_K + t * 8) = v;
    } else {
        const size_t nv = (size_t)N_N * D_K / 8;
        size_t stride = (size_t)(gridDim.x - M_M) * blockDim.x;
        for (size_t v = (size_t)(blockIdx.x - M_M) * blockDim.x + t; v < nv; v += stride) {
            const float4* p = reinterpret_cast<const float4*>(B) + v * 2;
            float4 a = p[0], b = p[1];
            bf16x8 o;
            o[0] = (short)f2bf(a.x); o[1] = (short)f2bf(a.y);
            o[2] = (short)f2bf(a.z); o[3] = (short)f2bf(a.w);
            o[4] = (short)f2bf(b.x); o[5] = (short)f2bf(b.y);
            o[6] = (short)f2bf(b.z); o[7] = (short)f2bf(b.w);
            reinterpret_cast<bf16x8*>(bbf)[v] = o;
        }
    }
}

// ---------------- pass 2: 256x256 GEMM, 32x32x16 MFMA, 2 phases/tile ------
// 512 threads = 8 waves (2M x 4N); wave output 128x64 = 4x2 subtiles of 32.
// LDS 128 KiB = buf[2] x {A 32K, B 32K}; region (mat, s) = 256 x 32 bf16.
// Phase (b, s): 12 ds_read_b128 + 2 stage calls -> barrier -> lgkmcnt(0) ->
// 16 MFMA 32x32x16 -> vmcnt(8) -> barrier.
// Ledger (4 VMEM ops/phase): steady 8 outstanding = [s1(T), s0(T+1)];
// P1 issues s1(T+1), vmcnt(8) retires s1(T) (read at P2); P2 issues s0(T+2),
// vmcnt(8) retires s0(T+1) (read at T+1 P1). WAR: s1(T+1)->buf b^1 (last
// read T-1 P2); s0(T+2)->buf b (last read T P1). Tail-clamped stages only
// touch the buffer the final tiles don't read (audited).
__global__ __launch_bounds__(512, 2) void gemm32_kernel(const unsigned short* __restrict__ Abf,
                                                        const unsigned short* __restrict__ Bbf,
                                                        float* __restrict__ C) {
    __shared__ __align__(16) unsigned short lds[65536];   // 128 KiB

    // 256 wgs = 4 Mtiles x 64 Ntiles; bijective XCD swizzle (256 % 8 == 0).
    int bid = blockIdx.x;
    int wg  = (bid & 7) * 32 + (bid >> 3);
    int tm  = wg & 3, tn = wg >> 2;
    int m_blk = tm * 256, n_blk = tn * 256;

    int t = threadIdx.x, lane = t & 63, w = t >> 6;
    int wm = w >> 2, wn = w & 3;                     // 2 x 4 wave grid

    // 32x32x16 fragment lane constants: row31 = lane&31, khalf = lane>>5.
    // slot(kk) = ((kk*2 + khalf) ^ ((row31>>1)&3)) * 16  [same quarter-wave
    // conflict pattern as the verified 16x16 read].
    int row31 = lane & 31, khalf = lane >> 5;
    int xorm  = (row31 >> 1) & 3;
    int slotk[2], aao[4], bbo[2];
    #pragma unroll
    for (int kk = 0; kk < 2; ++kk) slotk[kk] = ((kk * 2 + khalf) ^ xorm) * 16;
    #pragma unroll
    for (int rb = 0; rb < 4; ++rb) aao[rb] = (wm * 128 + rb * 32 + row31) * 64;
    #pragma unroll
    for (int cb = 0; cb < 2; ++cb) bbo[cb] = (wn * 64 + cb * 32 + row31) * 64;

    // stage source pointers (pre-swizzled global chunk per rule #21)
    const unsigned short* gA[2];
    const unsigned short* gB[2];
    int sdst[2];
    #pragma unroll
    for (int pass = 0; pass < 2; ++pass) {
        int r = pass * 128 + (t >> 2);
        int csrc = (t & 3) ^ ((r >> 1) & 3);
        gA[pass] = Abf + (size_t)(m_blk + r) * D_K + csrc * 8;
        gB[pass] = Bbf + (size_t)(n_blk + r) * D_K + csrc * 8;
        sdst[pass] = pass * 8192 + w * 1024;   // wave-uniform LDS dest base
    }

    // stage one half-tile: region (mat, s) of K-tile kt into buffer b
    auto stage = [&](int mat, int s, int b, int ktile) {
        int kt = ktile < 32 ? ktile : 31;              // tail clamp (dead regions)
        int koff = kt * 64 + s * 32;
        int ldsb = b * 65536 + mat * 32768 + s * 16384;
        GLOAD16((mat ? gB[0] : gA[0]) + koff, (char*)lds + ldsb + sdst[0]);
        GLOAD16((mat ? gB[1] : gA[1]) + koff, (char*)lds + ldsb + sdst[1]);
    };

    f32x16 acc[4][2] = {};

#define PHASE32(bb, ss, ST1, ST2)                                              \
    {                                                                          \
        char* abase = (char*)lds + (bb) * 65536 + (ss) * 16384;                \
        char* bbase = abase + 32768;                                           \
        bf16x8 af[4][2], bv[2][2];                                             \
        _Pragma("unroll")                                                      \
        for (int rb = 0; rb < 4; ++rb)                                         \
            _Pragma("unroll")                                                  \
            for (int kk = 0; kk < 2; ++kk)                                     \
                af[rb][kk] = *reinterpret_cast<const bf16x8*>(                 \
                    abase + aao[rb] + slotk[kk]);                              \
        _Pragma("unroll")                                                      \
        for (int cb = 0; cb < 2; ++cb)                                         \
            _Pragma("unroll")                                                  \
            for (int kk = 0; kk < 2; ++kk)                                     \
                bv[cb][kk] = *reinterpret_cast<const bf16x8*>(                 \
                    bbase + bbo[cb] + slotk[kk]);                              \
        ST1;                                                                   \
        ST2;                                                                   \
        asm volatile("s_barrier" ::: "memory");                                \
        asm volatile("s_waitcnt lgkmcnt(0)" ::: "memory");                     \
        __builtin_amdgcn_sched_barrier(0);                                     \
        __builtin_amdgcn_s_setprio(1);                                         \
        _Pragma("unroll")                                                      \
        for (int kk = 0; kk < 2; ++kk)                                         \
            _Pragma("unroll")                                                  \
            for (int rb = 0; rb < 4; ++rb)                                     \
                _Pragma("unroll")                                              \
                for (int cb = 0; cb < 2; ++cb)                                 \
                    acc[rb][cb] = __builtin_amdgcn_mfma_f32_32x32x16_bf16(     \
                        af[rb][kk], bv[cb][kk], acc[rb][cb], 0, 0, 0);         \
        __builtin_amdgcn_s_setprio(0);                                         \
        asm volatile("s_waitcnt vmcnt(8)" ::: "memory");                       \
        asm volatile("s_barrier" ::: "memory");                                \
    }

    // prologue: tile0 full -> buf0 (8 ops), tile1 s0 -> buf1 (4 ops);
    // vmcnt(8) retires tile0-s0 (read at T0 P1).
    stage(0, 0, 0, 0);
    stage(1, 0, 0, 0);
    stage(0, 1, 0, 0);
    stage(1, 1, 0, 0);
    stage(0, 0, 1, 1);
    stage(1, 0, 1, 1);
    asm volatile("s_waitcnt vmcnt(8)" ::: "memory");
    asm volatile("s_barrier" ::: "memory");

    for (int T = 0; T < 32; ++T) {
        int b = T & 1;
        PHASE32(b, 0, stage(0, 1, b ^ 1, T + 1), stage(1, 1, b ^ 1, T + 1))
        PHASE32(b, 1, stage(0, 0, b,     T + 2), stage(1, 0, b,     T + 2))
    }
#undef PHASE32

    // epilogue: 32x32 C/D layout col=lane&31, row=(r&3)+8*(r>>2)+4*khalf
    // [m74/m101-verified]
    #pragma unroll
    for (int rb = 0; rb < 4; ++rb)
        #pragma unroll
        for (int cb = 0; cb < 2; ++cb) {
            int colg = n_blk + wn * 64 + cb * 32 + row31;
            #pragma unroll
            for (int r = 0; r < 16; ++r) {
                int rowg = m_blk + wm * 128 + rb * 32 +
                           (r & 3) + 8 * (r >> 2) + 4 * khalf;
                C[(size_t)rowg * N_N + colg] = acc[rb][cb][r] * TEMP_INV;
            }
        }
}

// ================= fallback (round-1 fused fp32-staged kernel) ============
__global__ __launch_bounds__(256) void rnorm_kernel(const float* __restrict__ x,
                                                    float* __restrict__ rn) {
    int row = blockIdx.x;
    const float4* xr = reinterpret_cast<const float4*>(x + (size_t)row * D_K);
    int t = threadIdx.x;
    float4 a = xr[t];
    float4 b = xr[t + 256];
    float s = a.x*a.x + a.y*a.y + a.z*a.z + a.w*a.w
            + b.x*b.x + b.y*b.y + b.z*b.z + b.w*b.w;
    #pragma unroll
    for (int off = 32; off > 0; off >>= 1) s += __shfl_down(s, off);
    __shared__ float ps[4];
    int wave = t >> 6, lane = t & 63;
    if (lane == 0) ps[wave] = s;
    __syncthreads();
    if (t == 0) {
        float tot = ps[0] + ps[1] + ps[2] + ps[3];
        rn[row] = 1.0f / fmaxf(sqrtf(tot), 1e-12f);
    }
}

__global__ __launch_bounds__(256, 2) void gemm_kernel(const float* __restrict__ A,
                                                      const float* __restrict__ Bm,
                                                      const float* __restrict__ rn,
                                                      float* __restrict__ C) {
    constexpr int BK = 64;
    __shared__ __align__(16) short lAs[128 * BK];
    __shared__ __align__(16) short lBs[128 * BK];
    int bid = blockIdx.x;
    int nb  = (bid & 7) * 128 + (bid >> 3);
    int tm  = nb & 7;
    int tn  = nb >> 3;
    int m0 = tm * 128, n0 = tn * 128;
    int t = threadIdx.x;
    int lane = t & 63, w = t >> 6;
    int wr = (w >> 1) * 64, wc = (w & 1) * 64;
    f32x4 acc[4][4] = {};
    float4 ra[4][2], rb[4][2];
    float  sc[4];
    int    srow[4], sgrp[4];
    #pragma unroll
    for (int i = 0; i < 4; ++i) {
        int li = t + i * 256;
        srow[i] = li >> 3;
        sgrp[i] = li & 7;
        sc[i]   = rn[m0 + srow[i]];
    }
    auto load_tiles = [&](int kt) {
        int k0 = kt * BK;
        #pragma unroll
        for (int i = 0; i < 4; ++i) {
            const float4* pa = reinterpret_cast<const float4*>(
                A + (size_t)(m0 + srow[i]) * D_K + k0 + sgrp[i] * 8);
            ra[i][0] = pa[0]; ra[i][1] = pa[1];
            const float4* pb = reinterpret_cast<const float4*>(
                Bm + (size_t)(n0 + srow[i]) * D_K + k0 + sgrp[i] * 8);
            rb[i][0] = pb[0]; rb[i][1] = pb[1];
        }
    };
    auto write_tiles = [&]() {
        #pragma unroll
        for (int i = 0; i < 4; ++i) {
            int row = srow[i];
            int slotw = sgrp[i] ^ (row & 7);
            float s = sc[i];
            bf16x8 va, vb;
            va[0] = (short)f2bf(ra[i][0].x * s); va[1] = (short)f2bf(ra[i][0].y * s);
            va[2] = (short)f2bf(ra[i][0].z * s); va[3] = (short)f2bf(ra[i][0].w * s);
            va[4] = (short)f2bf(ra[i][1].x * s); va[5] = (short)f2bf(ra[i][1].y * s);
            va[6] = (short)f2bf(ra[i][1].z * s); va[7] = (short)f2bf(ra[i][1].w * s);
            vb[0] = (short)f2bf(rb[i][0].x); vb[1] = (short)f2bf(rb[i][0].y);
            vb[2] = (short)f2bf(rb[i][0].z); vb[3] = (short)f2bf(rb[i][0].w);
            vb[4] = (short)f2bf(rb[i][1].x); vb[5] = (short)f2bf(rb[i][1].y);
            vb[6] = (short)f2bf(rb[i][1].z); vb[7] = (short)f2bf(rb[i][1].w);
            *reinterpret_cast<bf16x8*>(&lAs[row * BK + slotw * 8]) = va;
            *reinterpret_cast<bf16x8*>(&lBs[row * BK + slotw * 8]) = vb;
        }
    };
    auto compute = [&]() {
        #pragma unroll
        for (int ks = 0; ks < 2; ++ks) {
            bf16x8 af[4], bfr[4];
            #pragma unroll
            for (int f = 0; f < 4; ++f) {
                int arow = wr + f * 16 + (lane & 15);
                int aslot = (ks * 4 + (lane >> 4)) ^ (arow & 7);
                af[f] = *reinterpret_cast<const bf16x8*>(&lAs[arow * BK + aslot * 8]);
                int brow = wc + f * 16 + (lane & 15);
                int bslot = (ks * 4 + (lane >> 4)) ^ (brow & 7);
                bfr[f] = *reinterpret_cast<const bf16x8*>(&lBs[brow * BK + bslot * 8]);
            }
            #pragma unroll
            for (int m = 0; m < 4; ++m)
                #pragma unroll
                for (int n = 0; n < 4; ++n)
                    acc[m][n] = __builtin_amdgcn_mfma_f32_16x16x32_bf16(
                        af[m], bfr[n], acc[m][n], 0, 0, 0);
        }
    };
    load_tiles(0);
    write_tiles();
    for (int kt = 1; kt < D_K / BK; ++kt) {
        __syncthreads();
        load_tiles(kt);
        compute();
        __syncthreads();
        write_tiles();
    }
    __syncthreads();
    compute();
    #pragma unroll
    for (int m = 0; m < 4; ++m) {
        int r = m0 + wr + m * 16 + (lane >> 4) * 4;
        #pragma unroll
        for (int j = 0; j < 4; ++j) {
            float* cp = C + (size_t)(r + j) * N_N + n0 + wc + (lane & 15);
            #pragma unroll
            for (int n = 0; n < 4; ++n)
                cp[n * 16] = acc[m][n][j] * TEMP_INV;
        }
    }
}

extern "C" void kernel_launch(void* const* d_in, const int* in_sizes, int n_in,
                              void* d_out, int out_size, void* d_ws, size_t ws_size,
                              hipStream_t stream) {
    const float* inputs   = (const float*)d_in[0];
    // d_in[1] = targets (unused by the forward output)
    const float* features = (const float*)d_in[2];
    float* out = (float*)d_out;

    const size_t needA = (size_t)M_M * D_K * 2;           // 4 MiB
    const size_t needB = (size_t)N_N * D_K * 2;           // 64 MiB
    if (ws_size >= needA + needB) {
        unsigned short* Abf = (unsigned short*)d_ws;
        unsigned short* Bbf = Abf + (size_t)M_M * D_K;
        prep_kernel<<<M_M + 2048, 256, 0, stream>>>(inputs, features, Abf, Bbf);
        gemm32_kernel<<<(M_M / 256) * (N_N / 256), 512, 0, stream>>>(Abf, Bbf, out);
    } else {
        float* rn = (float*)d_ws;   // 1024 floats
        rnorm_kernel<<<M_M, 256, 0, stream>>>(inputs, rn);
        gemm_kernel<<<(M_M / 128) * (N_N / 128), 256, 0, stream>>>(inputs, features, rn, out);
    }
}

// Round 14
// 109.642 us; speedup vs baseline: 1.0321x; 1.0321x over previous
//
#include <hip/hip_runtime.h>
#include <hip/hip_bf16.h>

// C[1024,16384] = l2norm_rows(inputs[1024,2048]) @ features[16384,2048]^T / 0.05
// Round 12 re-resubmit (2x infra failure, no kernel signal): 128x512 tile
// GEMM (same verified 16x16 MFMA + LDS pattern as R5/R8; only geometry
// changes). 2 phases/K-tile, 4 barriers/tile, 32 MFMA/phase. LDS 160 KB.

typedef short bf16x8 __attribute__((ext_vector_type(8)));
typedef float f32x4  __attribute__((ext_vector_type(4)));

#define D_K   2048
#define N_N   16384
#define M_M   1024
#define TEMP_INV 20.0f

__device__ __forceinline__ unsigned short f2bf(float f) {
    unsigned u = __builtin_bit_cast(unsigned, f);
    u += 0x7FFFu + ((u >> 16) & 1u);   // round-to-nearest-even (finite data)
    return (unsigned short)(u >> 16);
}

#define GLOAD16(g, l) __builtin_amdgcn_global_load_lds(                        \
    (const __attribute__((address_space(1))) unsigned int*)(g),                \
    (__attribute__((address_space(3))) unsigned int*)(l), 16, 0, 0)

// ---------------- pass 1: prep = anorm (blocks 0..1023) + bconv (rest) ----
__global__ __launch_bounds__(256) void prep_kernel(const float* __restrict__ x,
                                                   const float* __restrict__ B,
                                                   unsigned short* __restrict__ abf,
                                                   unsigned short* __restrict__ bbf) {
    int t = threadIdx.x;
    if (blockIdx.x < M_M) {
        int row = blockIdx.x;
        const float4* xr = reinterpret_cast<const float4*>(x + (size_t)row * D_K);
        float4 a = xr[t * 2];
        float4 b = xr[t * 2 + 1];
        float s = a.x*a.x + a.y*a.y + a.z*a.z + a.w*a.w
                + b.x*b.x + b.y*b.y + b.z*b.z + b.w*b.w;
        #pragma unroll
        for (int off = 32; off > 0; off >>= 1) s += __shfl_down(s, off);
        __shared__ float ps[4];
        __shared__ float sbc;
        if ((t & 63) == 0) ps[t >> 6] = s;
        __syncthreads();
        if (t == 0) {
            float tot = ps[0] + ps[1] + ps[2] + ps[3];
            sbc = 1.0f / fmaxf(sqrtf(tot), 1e-12f);
        }
        __syncthreads();
        float rs = sbc;
        bf16x8 v;
        v[0] = (short)f2bf(a.x * rs); v[1] = (short)f2bf(a.y * rs);
        v[2] = (short)f2bf(a.z * rs); v[3] = (short)f2bf(a.w * rs);
        v[4] = (short)f2bf(b.x * rs); v[5] = (short)f2bf(b.y * rs);
        v[6] = (short)f2bf(b.z * rs); v[7] = (short)f2bf(b.w * rs);
        *reinterpret_cast<bf16x8*>(abf + (size_t)row * D_K + t * 8) = v;
    } else {
        const size_t nv = (size_t)N_N * D_K / 8;
        size_t stride = (size_t)(gridDim.x - M_M) * blockDim.x;
        for (size_t v = (size_t)(blockIdx.x - M_M) * blockDim.x + t; v < nv; v += stride) {
            const float4* p = reinterpret_cast<const float4*>(B) + v * 2;
            float4 a = p[0], b = p[1];
            bf16x8 o;
            o[0] = (short)f2bf(a.x); o[1] = (short)f2bf(a.y);
            o[2] = (short)f2bf(a.z); o[3] = (short)f2bf(a.w);
            o[4] = (short)f2bf(b.x); o[5] = (short)f2bf(b.y);
            o[6] = (short)f2bf(b.z); o[7] = (short)f2bf(b.w);
            reinterpret_cast<bf16x8*>(bbf)[v] = o;
        }
    }
}

// ---------------- pass 2: 128x512 GEMM, 2 phases/tile ---------------------
// 512 threads = 8 waves (2M x 4N); wave tile 64x128 = 4x8 16x16 frags.
// LDS 160 KB = buf[2] x {A s0 8K, A s1 8K, B s0 32K, B s1 32K}.
// Phase P1(T): 12 ds_read (A s0 x4, B s0 x8) + stage s1(T+1)->buf^1 (5 ops)
//   -> barrier -> lgkmcnt(0) -> 32 MFMA -> vmcnt(10) -> barrier.
// Phase P2(T): reads s1, stage s0(T+2)->buf (5 ops), same tail.
// Ledger: 5 ops/phase; vmcnt(10) = all but last 2 phases' stages landed ->
// s-region retired >=1 phase before first read. WAR: s1(T+1) last read
// T-1.P2 (barrier between); s0(T+2) last read T.P1 (barrier between).
// LDS read slot formula identical to R5/R8 (measured 0 conflicts).
__global__ __launch_bounds__(512, 1) void gemmw_kernel(const unsigned short* __restrict__ Abf,
                                                       const unsigned short* __restrict__ Bbf,
                                                       float* __restrict__ C) {
    __shared__ __align__(16) unsigned short lds[81920];   // 160 KiB

    // 256 wgs = 8 Mtiles x 32 Ntiles; bijective XCD swizzle (256 % 8 == 0).
    // 8 tm-wgs per tn panel land consecutively -> same XCD shares B in L2.
    int bid = blockIdx.x;
    int wg  = (bid & 7) * 32 + (bid >> 3);
    int tm  = wg & 7, tn = wg >> 3;
    int m_blk = tm * 128, n_blk = tn * 512;

    int t = threadIdx.x, lane = t & 63, w = t >> 6;
    int wm = w >> 2, wn = w & 3;                     // 2 x 4 wave grid

    // ds_read lane constants (R5/R8-verified): slot = q ^ ((row>>1)&3)
    int l15  = lane & 15;
    int slot = ((lane >> 4) ^ ((l15 >> 1) & 3)) * 16;     // byte slot offset
    int aoff[4], boff[8];
    #pragma unroll
    for (int rb = 0; rb < 4; ++rb)
        aoff[rb] = (wm * 64 + rb * 16 + l15) * 64 + slot;
    #pragma unroll
    for (int cb = 0; cb < 8; ++cb)
        boff[cb] = (wn * 128 + cb * 16 + l15) * 64 + slot;

    // stage sources (pre-swizzled global chunk, rule #21), linear LDS dest
    int rA = t >> 2;
    int cA = (t & 3) ^ ((rA >> 1) & 3);
    const unsigned short* gA0 = Abf + (size_t)(m_blk + rA) * D_K + cA * 8;
    const unsigned short* gB[4];
    #pragma unroll
    for (int p = 0; p < 4; ++p) {
        int r = p * 128 + (t >> 2);
        int c = (t & 3) ^ ((r >> 1) & 3);
        gB[p] = Bbf + (size_t)(n_blk + r) * D_K + c * 8;
    }
    int sdst = w * 1024;

    // stage the s-half (A 8K + B 32K) of K-tile kt into buffer b: 5 ops
    auto stageS = [&](int s, int b, int ktile) {
        int kt = ktile < 32 ? ktile : 31;              // tail clamp (dead regions)
        int koff = kt * 64 + s * 32;
        char* dst = (char*)lds + b * 81920;
        GLOAD16(gA0 + koff, dst + s * 8192 + sdst);
        #pragma unroll
        for (int p = 0; p < 4; ++p)
            GLOAD16(gB[p] + koff, dst + 16384 + s * 32768 + p * 8192 + sdst);
    };

    f32x4 acc[4][8] = {};

#define PHASEW(b, s, STS, STB, STKT)                                           \
    {                                                                          \
        char* base = (char*)lds + (b) * 81920;                                 \
        bf16x8 af[4], bv[8];                                                   \
        _Pragma("unroll")                                                      \
        for (int rb = 0; rb < 4; ++rb)                                         \
            af[rb] = *reinterpret_cast<const bf16x8*>(                         \
                base + (s) * 8192 + aoff[rb]);                                 \
        _Pragma("unroll")                                                      \
        for (int cb = 0; cb < 8; ++cb)                                         \
            bv[cb] = *reinterpret_cast<const bf16x8*>(                         \
                base + 16384 + (s) * 32768 + boff[cb]);                        \
        stageS(STS, STB, STKT);                                                \
        asm volatile("s_barrier" ::: "memory");                                \
        asm volatile("s_waitcnt lgkmcnt(0)" ::: "memory");                     \
        __builtin_amdgcn_sched_barrier(0);                                     \
        __builtin_amdgcn_s_setprio(1);                                         \
        _Pragma("unroll")                                                      \
        for (int cb = 0; cb < 8; ++cb)                                         \
            _Pragma("unroll")                                                  \
            for (int rb = 0; rb < 4; ++rb)                                     \
                acc[rb][cb] = __builtin_amdgcn_mfma_f32_16x16x32_bf16(         \
                    af[rb], bv[cb], acc[rb][cb], 0, 0, 0);                     \
        __builtin_amdgcn_s_setprio(0);                                         \
        asm volatile("s_waitcnt vmcnt(10)" ::: "memory");                      \
        asm volatile("s_barrier" ::: "memory");                                \
    }

    // prologue: s0(0), s1(0) -> buf0; s0(1) -> buf1 (15 ops);
    // vmcnt(10) retires tile0-s0.
    stageS(0, 0, 0);
    stageS(1, 0, 0);
    stageS(0, 1, 1);
    asm volatile("s_waitcnt vmcnt(10)" ::: "memory");
    asm volatile("s_barrier" ::: "memory");

    for (int T = 0; T < 32; ++T) {
        int b = T & 1;
        PHASEW(b, 0, 1, b ^ 1, T + 1)    // stage s1(T+1) -> other buffer
        PHASEW(b, 1, 0, b,     T + 2)    // stage s0(T+2) -> this buffer
    }
#undef PHASEW

    // epilogue: C/D layout col=lane&15, row=(lane>>4)*4+j [m89-verified]
    #pragma unroll
    for (int rb = 0; rb < 4; ++rb) {
        int r = m_blk + wm * 64 + rb * 16 + (lane >> 4) * 4;
        #pragma unroll
        for (int j = 0; j < 4; ++j) {
            float* cp = C + (size_t)(r + j) * N_N + n_blk + wn * 128 + (lane & 15);
            #pragma unroll
            for (int cb = 0; cb < 8; ++cb)
                cp[cb * 16] = acc[rb][cb][j] * TEMP_INV;
        }
    }
}

// ================= fallback (round-1 fused fp32-staged kernel) ============
__global__ __launch_bounds__(256) void rnorm_kernel(const float* __restrict__ x,
                                                    float* __restrict__ rn) {
    int row = blockIdx.x;
    const float4* xr = reinterpret_cast<const float4*>(x + (size_t)row * D_K);
    int t = threadIdx.x;
    float4 a = xr[t];
    float4 b = xr[t + 256];
    float s = a.x*a.x + a.y*a.y + a.z*a.z + a.w*a.w
            + b.x*b.x + b.y*b.y + b.z*b.z + b.w*b.w;
    #pragma unroll
    for (int off = 32; off > 0; off >>= 1) s += __shfl_down(s, off);
    __shared__ float ps[4];
    int wave = t >> 6, lane = t & 63;
    if (lane == 0) ps[wave] = s;
    __syncthreads();
    if (t == 0) {
        float tot = ps[0] + ps[1] + ps[2] + ps[3];
        rn[row] = 1.0f / fmaxf(sqrtf(tot), 1e-12f);
    }
}

__global__ __launch_bounds__(256, 2) void gemm_kernel(const float* __restrict__ A,
                                                      const float* __restrict__ Bm,
                                                      const float* __restrict__ rn,
                                                      float* __restrict__ C) {
    constexpr int BK = 64;
    __shared__ __align__(16) short lAs[128 * BK];
    __shared__ __align__(16) short lBs[128 * BK];
    int bid = blockIdx.x;
    int nb  = (bid & 7) * 128 + (bid >> 3);
    int tm  = nb & 7;
    int tn  = nb >> 3;
    int m0 = tm * 128, n0 = tn * 128;
    int t = threadIdx.x;
    int lane = t & 63, w = t >> 6;
    int wr = (w >> 1) * 64, wc = (w & 1) * 64;
    f32x4 acc[4][4] = {};
    float4 ra[4][2], rb[4][2];
    float  sc[4];
    int    srow[4], sgrp[4];
    #pragma unroll
    for (int i = 0; i < 4; ++i) {
        int li = t + i * 256;
        srow[i] = li >> 3;
        sgrp[i] = li & 7;
        sc[i]   = rn[m0 + srow[i]];
    }
    auto load_tiles = [&](int kt) {
        int k0 = kt * BK;
        #pragma unroll
        for (int i = 0; i < 4; ++i) {
            const float4* pa = reinterpret_cast<const float4*>(
                A + (size_t)(m0 + srow[i]) * D_K + k0 + sgrp[i] * 8);
            ra[i][0] = pa[0]; ra[i][1] = pa[1];
            const float4* pb = reinterpret_cast<const float4*>(
                Bm + (size_t)(n0 + srow[i]) * D_K + k0 + sgrp[i] * 8);
            rb[i][0] = pb[0]; rb[i][1] = pb[1];
        }
    };
    auto write_tiles = [&]() {
        #pragma unroll
        for (int i = 0; i < 4; ++i) {
            int row = srow[i];
            int slotw = sgrp[i] ^ (row & 7);
            float s = sc[i];
            bf16x8 va, vb;
            va[0] = (short)f2bf(ra[i][0].x * s); va[1] = (short)f2bf(ra[i][0].y * s);
            va[2] = (short)f2bf(ra[i][0].z * s); va[3] = (short)f2bf(ra[i][0].w * s);
            va[4] = (short)f2bf(ra[i][1].x * s); va[5] = (short)f2bf(ra[i][1].y * s);
            va[6] = (short)f2bf(ra[i][1].z * s); va[7] = (short)f2bf(ra[i][1].w * s);
            vb[0] = (short)f2bf(rb[i][0].x); vb[1] = (short)f2bf(rb[i][0].y);
            vb[2] = (short)f2bf(rb[i][0].z); vb[3] = (short)f2bf(rb[i][0].w);
            vb[4] = (short)f2bf(rb[i][1].x); vb[5] = (short)f2bf(rb[i][1].y);
            vb[6] = (short)f2bf(rb[i][1].z); vb[7] = (short)f2bf(rb[i][1].w);
            *reinterpret_cast<bf16x8*>(&lAs[row * BK + slotw * 8]) = va;
            *reinterpret_cast<bf16x8*>(&lBs[row * BK + slotw * 8]) = vb;
        }
    };
    auto compute = [&]() {
        #pragma unroll
        for (int ks = 0; ks < 2; ++ks) {
            bf16x8 af[4], bfr[4];
            #pragma unroll
            for (int f = 0; f < 4; ++f) {
                int arow = wr + f * 16 + (lane & 15);
                int aslot = (ks * 4 + (lane >> 4)) ^ (arow & 7);
                af[f] = *reinterpret_cast<const bf16x8*>(&lAs[arow * BK + aslot * 8]);
                int brow = wc + f * 16 + (lane & 15);
                int bslot = (ks * 4 + (lane >> 4)) ^ (brow & 7);
                bfr[f] = *reinterpret_cast<const bf16x8*>(&lBs[brow * BK + bslot * 8]);
            }
            #pragma unroll
            for (int m = 0; m < 4; ++m)
                #pragma unroll
                for (int n = 0; n < 4; ++n)
                    acc[m][n] = __builtin_amdgcn_mfma_f32_16x16x32_bf16(
                        af[m], bfr[n], acc[m][n], 0, 0, 0);
        }
    };
    load_tiles(0);
    write_tiles();
    for (int kt = 1; kt < D_K / BK; ++kt) {
        __syncthreads();
        load_tiles(kt);
        compute();
        __syncthreads();
        write_tiles();
    }
    __syncthreads();
    compute();
    #pragma unroll
    for (int m = 0; m < 4; ++m) {
        int r = m0 + wr + m * 16 + (lane >> 4) * 4;
        #pragma unroll
        for (int j = 0; j < 4; ++j) {
            float* cp = C + (size_t)(r + j) * N_N + n0 + wc + (lane & 15);
            #pragma unroll
            for (int n = 0; n < 4; ++n)
                cp[n * 16] = acc[m][n][j] * TEMP_INV;
        }
    }
}

extern "C" void kernel_launch(void* const* d_in, const int* in_sizes, int n_in,
                              void* d_out, int out_size, void* d_ws, size_t ws_size,
                              hipStream_t stream) {
    const float* inputs   = (const float*)d_in[0];
    // d_in[1] = targets (unused by the forward output)
    const float* features = (const float*)d_in[2];
    float* out = (float*)d_out;

    const size_t needA = (size_t)M_M * D_K * 2;           // 4 MiB
    const size_t needB = (size_t)N_N * D_K * 2;           // 64 MiB
    if (ws_size >= needA + needB) {
        unsigned short* Abf = (unsigned short*)d_ws;
        unsigned short* Bbf = Abf + (size_t)M_M * D_K;
        prep_kernel<<<M_M + 2048, 256, 0, stream>>>(inputs, features, Abf, Bbf);
        gemmw_kernel<<<(M_M / 128) * (N_N / 512), 512, 0, stream>>>(Abf, Bbf, out);
    } else {
        float* rn = (float*)d_ws;   // 1024 floats
        rnorm_kernel<<<M_M, 256, 0, stream>>>(inputs, rn);
        gemm_kernel<<<(M_M / 128) * (N_N / 128), 256, 0, stream>>>(inputs, features, rn, out);
    }
}